// Round 14
// baseline (975.265 us; speedup 1.0000x reference)
//
#include <hip/hip_runtime.h>
#include <math.h>

// ---------------------------------------------------------------------------
// GNN: 3x GatedGraphConv (C=32,64,128; 4 inner layers each) + BN + pool + MLP
// Round 14: GRU blocks halved to 2 waves / 32 nodes (grid 2x -> finer tail,
// 6.1 blocks/CU instead of 3.05; B refetch stays L2-resident). Math identical
// to round 13: S hi-only, H split hi/lo, Wc fold, out-of-place ping-pong.
// ---------------------------------------------------------------------------

#define EPS_BN 1e-5f

typedef short short8 __attribute__((ext_vector_type(8)));
typedef unsigned short u16x8 __attribute__((ext_vector_type(8)));
typedef float f32x4 __attribute__((ext_vector_type(4)));

__device__ __forceinline__ float elu_f(float v) {
    return v > 0.f ? v : expm1f(v);
}
__device__ __forceinline__ float sigmoid_f(float v) {
    return 1.f / (1.f + __expf(-v));
}
__device__ __forceinline__ float tanh_f(float v) {
    float e = __expf(2.f * v);
    return 1.f - 2.f / (e + 1.f);
}
__device__ __forceinline__ unsigned short f2bf(float f) {
    unsigned u = __float_as_uint(f);
    unsigned r = (u + 0x7FFF + ((u >> 16) & 1)) >> 16;
    return (unsigned short)r;
}
__device__ __forceinline__ float bf2f(unsigned short b) {
    return __uint_as_float(((unsigned)b) << 16);
}
__device__ __forceinline__ void put_hl(unsigned short* __restrict__ hi,
                                       unsigned short* __restrict__ lo,
                                       size_t idx, float v) {
    unsigned short h = f2bf(v);
    hi[idx] = h;
    lo[idx] = f2bf(v - bf2f(h));
}

// ------------------------- CSR construction -------------------------------

__global__ __launch_bounds__(256) void hist_kernel(
    const int* __restrict__ ei, int* __restrict__ deg, int E) {
    int e = blockIdx.x * 256 + threadIdx.x;
    if (e < E) atomicAdd(&deg[ei[E + e]], 1);
}

__global__ __launch_bounds__(256) void scan1_kernel(
    const int* __restrict__ deg, int* __restrict__ out,
    int* __restrict__ blockSums, int N) {
    __shared__ int sdata[256];
    int b = blockIdx.x, t = threadIdx.x;
    int base = b * 1024 + t * 4;
    int v[4], s = 0;
#pragma unroll
    for (int i = 0; i < 4; ++i) {
        v[i] = (base + i < N) ? deg[base + i] : 0;
        s += v[i];
    }
    sdata[t] = s;
    __syncthreads();
    for (int off = 1; off < 256; off <<= 1) {
        int x = (t >= off) ? sdata[t - off] : 0;
        __syncthreads();
        sdata[t] += x;
        __syncthreads();
    }
    int run = sdata[t] - s;
#pragma unroll
    for (int i = 0; i < 4; ++i) {
        if (base + i < N) out[base + i] = run;
        run += v[i];
    }
    if (t == 255) blockSums[b] = sdata[255];
}

__global__ void scan2_kernel(int* blockSums, int nb) {
    if (threadIdx.x == 0 && blockIdx.x == 0) {
        int run = 0;
        for (int i = 0; i < nb; ++i) {
            int v = blockSums[i];
            blockSums[i] = run;
            run += v;
        }
    }
}

__global__ __launch_bounds__(256) void scan3_kernel(
    const int* __restrict__ out, const int* __restrict__ blockSums,
    int* __restrict__ rowstart, int* __restrict__ writeptr, int N, int E) {
    int i = blockIdx.x * 256 + threadIdx.x;
    if (i < N) {
        int v = out[i] + blockSums[i >> 10];
        rowstart[i] = v;
        writeptr[i] = v;
    }
    if (i == 0) rowstart[N] = E;
}

__global__ __launch_bounds__(256) void fill_kernel(
    const int* __restrict__ ei, int* __restrict__ writeptr,
    int* __restrict__ csr_src, int E) {
    int e = blockIdx.x * 256 + threadIdx.x;
    if (e < E) {
        int d = ei[E + e];
        int p = atomicAdd(&writeptr[d], 1);
        csr_src[p] = ei[e];
    }
}

// ------------------------- Wc = W[l] @ wih^T ------------------------------

template <int C>
__global__ __launch_bounds__(256) void wc_kernel(
    const float* __restrict__ W, const float* __restrict__ wih,
    float* __restrict__ Wc) {
    int idx = blockIdx.x * 256 + threadIdx.x;
    if (idx >= 4 * C * 3 * C) return;
    int l = idx / (C * 3 * C);
    int r = idx % (C * 3 * C);
    int k = r / (3 * C);
    int row = r % (3 * C);
    const float* wrow = W + ((size_t)l * C + k) * C;
    const float* irow = wih + (size_t)row * C;
    float acc = 0.f;
#pragma unroll 4
    for (int t = 0; t < C; ++t) acc += wrow[t] * irow[t];
    Wc[idx] = acc;
}

// ------------------------- B2 swizzle (hi/lo, all 4 layers) ---------------
// mfma_f32_16x16x32_bf16:
//   A[m][k]: m = lane&15, k = (lane>>4)*8 + j
//   B[k][n]: n = lane&15, k = (lane>>4)*8 + j
//   C/D:     col = lane&15, row = (lane>>4)*4 + reg
// GRU concat-B: K = 2C (k<C: Wc_l on S; k>=C: whh on H).
// tslot per ks: [0,CT): r ; [CT,2CT): z ; [2CT,3CT): k<C ? in : hn

template <int C>
__global__ __launch_bounds__(256) void swizzle_b2_kernel(
    const float* __restrict__ Wc, const float* __restrict__ whh,
    unsigned short* __restrict__ BsHi, unsigned short* __restrict__ BsLo) {
    constexpr int CT = C / 16;
    int idx = blockIdx.x * 256 + threadIdx.x;
    if (idx >= 4 * 6 * C * C) return;
    int l = idx / (6 * C * C);
    int r0 = idx % (6 * C * C);
    int j = r0 & 7;
    int lane = (r0 >> 3) & 63;
    int rest = r0 >> 9;
    int tslot = rest % (3 * CT);
    int ks = rest / (3 * CT);
    int k = ks * 32 + (lane >> 4) * 8 + j;
    int g = tslot / CT;
    int lt = tslot % CT;
    int c = lt * 16 + (lane & 15);
    int row = g * C + c;
    float v = (k < C) ? Wc[((size_t)l * C + k) * 3 * C + row]
                      : whh[(size_t)row * C + (k - C)];
    unsigned short h = f2bf(v);
    BsHi[idx] = h;
    BsLo[idx] = f2bf(v - bf2f(h));
}

// ------------------------- gather: S[d] = sum X[src] ----------------------
// LPG = C/8 lanes per dst, 16B loads, 4-edge unrolled pipeline.
// Reads only the HI plane of neighbors; sums fp32; writes S HI-ONLY.

template <int C>
__global__ __launch_bounds__(256) void gather_kernel(
    const unsigned short* __restrict__ Xhi,
    const int* __restrict__ rowstart, const int* __restrict__ csr_src,
    unsigned short* __restrict__ Shi, int N) {
    constexpr int LPG = C / 8;
    constexpr int GPB = 256 / LPG;
    int lane = threadIdx.x % LPG;
    int grp = threadIdx.x / LPG;
    int d = blockIdx.x * GPB + grp;
    if (d >= N) return;
    int p = rowstart[d];
    int p1 = rowstart[d + 1];
    float a[8];
#pragma unroll
    for (int j = 0; j < 8; ++j) a[j] = 0.f;
    int off = lane * 8;
    for (; p + 3 < p1; p += 4) {
        int s0 = csr_src[p];
        int s1 = csr_src[p + 1];
        int s2 = csr_src[p + 2];
        int s3 = csr_src[p + 3];
        u16x8 h0 = *(const u16x8*)(Xhi + (size_t)s0 * C + off);
        u16x8 h1 = *(const u16x8*)(Xhi + (size_t)s1 * C + off);
        u16x8 h2 = *(const u16x8*)(Xhi + (size_t)s2 * C + off);
        u16x8 h3 = *(const u16x8*)(Xhi + (size_t)s3 * C + off);
#pragma unroll
        for (int j = 0; j < 8; ++j) {
            a[j] += (bf2f(h0[j]) + bf2f(h1[j])) + (bf2f(h2[j]) + bf2f(h3[j]));
        }
    }
    for (; p < p1; ++p) {
        int s0 = csr_src[p];
        u16x8 h0 = *(const u16x8*)(Xhi + (size_t)s0 * C + off);
#pragma unroll
        for (int j = 0; j < 8; ++j) a[j] += bf2f(h0[j]);
    }
    size_t base = (size_t)d * C + off;
#pragma unroll
    for (int j = 0; j < 8; ++j) Shi[base + j] = f2bf(a[j]);
}

// ------------------------- GRU cell (C = 64 / 128) ------------------------
// Block = 2 waves = 32 nodes (2 A-tiles). Wave w owns column tiles
// [w*CTW,(w+1)*CTW) of every gate (CTW = CT/2) -> gate combine wave-local.
// Out-of-place: reads Hin/S, writes Hout (no races).
// S-half: A hi-only (2 MFMA ops/acc). H-half: full split (3 ops/acc).
// 2-wave blocks double the grid (finer tail, more independent blocks/CU);
// per-wave MFMA count and acc-register budget unchanged vs 4-wave shape.

template <int C, int MINW>
__global__ __launch_bounds__(128, MINW) void gru_mfma_kernel(
    const unsigned short* __restrict__ HinHi, const unsigned short* __restrict__ HinLo,
    unsigned short* __restrict__ HoutHi, unsigned short* __restrict__ HoutLo,
    const unsigned short* __restrict__ Shi,
    const unsigned short* __restrict__ BsHi, const unsigned short* __restrict__ BsLo,
    const float* __restrict__ biasI, const float* __restrict__ biasH, int N) {
    constexpr int CT = C / 16;
    constexpr int KS = C / 16;   // 2C/32 k-steps
    constexpr int CTW = CT / 2;  // column tiles per wave per gate
    int wave = threadIdx.x >> 6;
    int lane = threadIdx.x & 63;
    int quad = lane >> 4;
    int l16 = lane & 15;
    int node0 = blockIdx.x * 32;
    int arow[2];
#pragma unroll
    for (int t = 0; t < 2; ++t) {
        int r = node0 + t * 16 + l16;
        arow[t] = r < N ? r : N - 1;
    }
    f32x4 accR[CTW][2], accZ[CTW][2], accN[CTW][2], accH[CTW][2];
#pragma unroll
    for (int ct = 0; ct < CTW; ++ct)
#pragma unroll
        for (int t = 0; t < 2; ++t) {
            accR[ct][t] = (f32x4){0.f, 0.f, 0.f, 0.f};
            accZ[ct][t] = (f32x4){0.f, 0.f, 0.f, 0.f};
            accN[ct][t] = (f32x4){0.f, 0.f, 0.f, 0.f};
            accH[ct][t] = (f32x4){0.f, 0.f, 0.f, 0.f};
        }
    const short8* bhi = (const short8*)BsHi;
    const short8* blo = (const short8*)BsLo;

    // ---- S half (k < C): A = Shi only (2 MFMA ops per acc) ----
    for (int ks = 0; ks < KS / 2; ++ks) {
        int k0 = ks * 32 + quad * 8;
        short8 ahi[2];
#pragma unroll
        for (int t = 0; t < 2; ++t)
            ahi[t] = *(const short8*)(Shi + (size_t)arow[t] * C + k0);
#pragma unroll
        for (int ct = 0; ct < CTW; ++ct) {
            int ts = ks * 3 * CT + wave * CTW + ct;
            short8 bhf = bhi[(size_t)ts * 64 + lane];
            short8 blf = blo[(size_t)ts * 64 + lane];
#pragma unroll
            for (int t = 0; t < 2; ++t) {
                accR[ct][t] = __builtin_amdgcn_mfma_f32_16x16x32_bf16(ahi[t], bhf, accR[ct][t], 0, 0, 0);
                accR[ct][t] = __builtin_amdgcn_mfma_f32_16x16x32_bf16(ahi[t], blf, accR[ct][t], 0, 0, 0);
            }
            bhf = bhi[(size_t)(ts + CT) * 64 + lane];
            blf = blo[(size_t)(ts + CT) * 64 + lane];
#pragma unroll
            for (int t = 0; t < 2; ++t) {
                accZ[ct][t] = __builtin_amdgcn_mfma_f32_16x16x32_bf16(ahi[t], bhf, accZ[ct][t], 0, 0, 0);
                accZ[ct][t] = __builtin_amdgcn_mfma_f32_16x16x32_bf16(ahi[t], blf, accZ[ct][t], 0, 0, 0);
            }
            bhf = bhi[(size_t)(ts + 2 * CT) * 64 + lane];
            blf = blo[(size_t)(ts + 2 * CT) * 64 + lane];
#pragma unroll
            for (int t = 0; t < 2; ++t) {
                accN[ct][t] = __builtin_amdgcn_mfma_f32_16x16x32_bf16(ahi[t], bhf, accN[ct][t], 0, 0, 0);
                accN[ct][t] = __builtin_amdgcn_mfma_f32_16x16x32_bf16(ahi[t], blf, accN[ct][t], 0, 0, 0);
            }
        }
    }
    // ---- H half (k >= C): A = Hin hi/lo (3 MFMA ops per acc) ----
    for (int ks = KS / 2; ks < KS; ++ks) {
        int k0 = ks * 32 + quad * 8 - C;
        short8 ahi[2], alo[2];
#pragma unroll
        for (int t = 0; t < 2; ++t) {
            ahi[t] = *(const short8*)(HinHi + (size_t)arow[t] * C + k0);
            alo[t] = *(const short8*)(HinLo + (size_t)arow[t] * C + k0);
        }
#pragma unroll
        for (int ct = 0; ct < CTW; ++ct) {
            int ts = ks * 3 * CT + wave * CTW + ct;
            short8 bhf = bhi[(size_t)ts * 64 + lane];
            short8 blf = blo[(size_t)ts * 64 + lane];
#pragma unroll
            for (int t = 0; t < 2; ++t) {
                accR[ct][t] = __builtin_amdgcn_mfma_f32_16x16x32_bf16(ahi[t], bhf, accR[ct][t], 0, 0, 0);
                accR[ct][t] = __builtin_amdgcn_mfma_f32_16x16x32_bf16(alo[t], bhf, accR[ct][t], 0, 0, 0);
                accR[ct][t] = __builtin_amdgcn_mfma_f32_16x16x32_bf16(ahi[t], blf, accR[ct][t], 0, 0, 0);
            }
            bhf = bhi[(size_t)(ts + CT) * 64 + lane];
            blf = blo[(size_t)(ts + CT) * 64 + lane];
#pragma unroll
            for (int t = 0; t < 2; ++t) {
                accZ[ct][t] = __builtin_amdgcn_mfma_f32_16x16x32_bf16(ahi[t], bhf, accZ[ct][t], 0, 0, 0);
                accZ[ct][t] = __builtin_amdgcn_mfma_f32_16x16x32_bf16(alo[t], bhf, accZ[ct][t], 0, 0, 0);
                accZ[ct][t] = __builtin_amdgcn_mfma_f32_16x16x32_bf16(ahi[t], blf, accZ[ct][t], 0, 0, 0);
            }
            bhf = bhi[(size_t)(ts + 2 * CT) * 64 + lane];
            blf = blo[(size_t)(ts + 2 * CT) * 64 + lane];
#pragma unroll
            for (int t = 0; t < 2; ++t) {
                accH[ct][t] = __builtin_amdgcn_mfma_f32_16x16x32_bf16(ahi[t], bhf, accH[ct][t], 0, 0, 0);
                accH[ct][t] = __builtin_amdgcn_mfma_f32_16x16x32_bf16(alo[t], bhf, accH[ct][t], 0, 0, 0);
                accH[ct][t] = __builtin_amdgcn_mfma_f32_16x16x32_bf16(ahi[t], blf, accH[ct][t], 0, 0, 0);
            }
        }
    }

#pragma unroll
    for (int ct = 0; ct < CTW; ++ct) {
        int c = (wave * CTW + ct) * 16 + l16;
        float bir = biasI[c], biz = biasI[C + c], bin = biasI[2 * C + c];
        float bhr = biasH[c], bhz = biasH[C + c], bhn = biasH[2 * C + c];
#pragma unroll
        for (int t = 0; t < 2; ++t) {
#pragma unroll
            for (int r = 0; r < 4; ++r) {
                int node = node0 + t * 16 + quad * 4 + r;
                if (node < N) {
                    size_t gi = (size_t)node * C + c;
                    float xo = bf2f(HinHi[gi]) + bf2f(HinLo[gi]);
                    float rv = sigmoid_f(accR[ct][t][r] + bir + bhr);
                    float zv = sigmoid_f(accZ[ct][t][r] + biz + bhz);
                    float nv = tanh_f(accN[ct][t][r] + bin + rv * (accH[ct][t][r] + bhn));
                    put_hl(HoutHi, HoutLo, gi, (1.f - zv) * nv + zv * xo);
                }
            }
        }
    }
}

// C=32 GRU: 1 A-tile per wave, out-of-place; S hi-only
__global__ __launch_bounds__(256, 4) void gru32_kernel(
    const unsigned short* __restrict__ HinHi, const unsigned short* __restrict__ HinLo,
    unsigned short* __restrict__ HoutHi, unsigned short* __restrict__ HoutLo,
    const unsigned short* __restrict__ Shi,
    const unsigned short* __restrict__ BsHi, const unsigned short* __restrict__ BsLo,
    const float* __restrict__ biasI, const float* __restrict__ biasH, int N) {
    constexpr int C = 32;
    constexpr int CT = 2;
    int wave = threadIdx.x >> 6;
    int lane = threadIdx.x & 63;
    int quad = lane >> 4;
    int l16 = lane & 15;
    int node0 = blockIdx.x * 64 + wave * 16;
    int ar = node0 + l16;
    if (ar >= N) ar = N - 1;
    f32x4 accR[CT], accZ[CT], accN[CT], accH[CT];
#pragma unroll
    for (int t = 0; t < CT; ++t) {
        accR[t] = (f32x4){0.f, 0.f, 0.f, 0.f};
        accZ[t] = (f32x4){0.f, 0.f, 0.f, 0.f};
        accN[t] = (f32x4){0.f, 0.f, 0.f, 0.f};
        accH[t] = (f32x4){0.f, 0.f, 0.f, 0.f};
    }
    const short8* bhi = (const short8*)BsHi;
    const short8* blo = (const short8*)BsLo;
    int k0 = quad * 8;
    {  // ks = 0: S half (hi-only, 2 ops)
        short8 ahi = *(const short8*)(Shi + (size_t)ar * C + k0);
#pragma unroll
        for (int g = 0; g < 3; ++g) {
            f32x4* acc = g == 0 ? accR : (g == 1 ? accZ : accN);
#pragma unroll
            for (int t = 0; t < CT; ++t) {
                int ts = g * CT + t;
                short8 bhf = bhi[(size_t)ts * 64 + lane];
                short8 blf = blo[(size_t)ts * 64 + lane];
                acc[t] = __builtin_amdgcn_mfma_f32_16x16x32_bf16(ahi, bhf, acc[t], 0, 0, 0);
                acc[t] = __builtin_amdgcn_mfma_f32_16x16x32_bf16(ahi, blf, acc[t], 0, 0, 0);
            }
        }
    }
    {  // ks = 1: H half (full split, 3 ops)
        short8 ahi = *(const short8*)(HinHi + (size_t)ar * C + k0);
        short8 alo = *(const short8*)(HinLo + (size_t)ar * C + k0);
#pragma unroll
        for (int g = 0; g < 3; ++g) {
            f32x4* acc = g == 0 ? accR : (g == 1 ? accZ : accH);
#pragma unroll
            for (int t = 0; t < CT; ++t) {
                int ts = 3 * CT + g * CT + t;
                short8 bhf = bhi[(size_t)ts * 64 + lane];
                short8 blf = blo[(size_t)ts * 64 + lane];
                acc[t] = __builtin_amdgcn_mfma_f32_16x16x32_bf16(ahi, bhf, acc[t], 0, 0, 0);
                acc[t] = __builtin_amdgcn_mfma_f32_16x16x32_bf16(alo, bhf, acc[t], 0, 0, 0);
                acc[t] = __builtin_amdgcn_mfma_f32_16x16x32_bf16(ahi, blf, acc[t], 0, 0, 0);
            }
        }
    }
#pragma unroll
    for (int t = 0; t < CT; ++t) {
        int c = t * 16 + l16;
        float bir = biasI[c], biz = biasI[C + c], bin = biasI[2 * C + c];
        float bhr = biasH[c], bhz = biasH[C + c], bhn = biasH[2 * C + c];
#pragma unroll
        for (int r = 0; r < 4; ++r) {
            int node = node0 + quad * 4 + r;
            if (node < N) {
                size_t gi = (size_t)node * C + c;
                float xo = bf2f(HinHi[gi]) + bf2f(HinLo[gi]);
                float rv = sigmoid_f(accR[t][r] + bir + bhr);
                float zv = sigmoid_f(accZ[t][r] + biz + bhz);
                float nv = tanh_f(accN[t][r] + bin + rv * (accH[t][r] + bhn));
                put_hl(HoutHi, HoutLo, gi, (1.f - zv) * nv + zv * xo);
            }
        }
    }
}

// ------------------------- epilogues --------------------------------------

__global__ __launch_bounds__(256) void init_x_kernel(
    const float* __restrict__ x, unsigned short* __restrict__ Hhi,
    unsigned short* __restrict__ Hlo, int total) {
    int t = blockIdx.x * 256 + threadIdx.x;
    if (t < total) put_hl(Hhi, Hlo, t, x[t]);
}

template <int Cin, int Cout>
__global__ __launch_bounds__(256) void elu_bn_pad_kernel(
    const unsigned short* __restrict__ Shi, const unsigned short* __restrict__ Slo,
    unsigned short* __restrict__ Dhi, unsigned short* __restrict__ Dlo,
    const float* __restrict__ gamma, const float* __restrict__ beta,
    const float* __restrict__ mean, const float* __restrict__ var, int N) {
    long t = (long)blockIdx.x * 256 + threadIdx.x;
    long total = (long)N * Cout;
    if (t >= total) return;
    int n = (int)(t / Cout);
    int c = (int)(t & (Cout - 1));
    float v = 0.f;
    if (c < Cin) {
        size_t si = (size_t)n * Cin + c;
        float x = bf2f(Shi[si]) + bf2f(Slo[si]);
        x = elu_f(x);
        v = (x - mean[c]) * rsqrtf(var[c] + EPS_BN) * gamma[c] + beta[c];
    }
    put_hl(Dhi, Dlo, t, v);
}

__global__ __launch_bounds__(256) void pool_elu_kernel(
    const unsigned short* __restrict__ Hhi, const unsigned short* __restrict__ Hlo,
    const int* __restrict__ batch, float* __restrict__ G, int N) {
    long t = (long)blockIdx.x * 256 + threadIdx.x;
    if (t >= (long)N * 128) return;
    int n = (int)(t >> 7);
    int c = (int)(t & 127);
    float v = elu_f(bf2f(Hhi[t]) + bf2f(Hlo[t]));
    atomicAdd(&G[batch[n] * 128 + c], v);
}

__global__ __launch_bounds__(256) void fc1_kernel(
    const float* __restrict__ G, const float* __restrict__ W,
    const float* __restrict__ b, float* __restrict__ G2) {
    __shared__ float row[128];
    int g = blockIdx.x;
    int j = threadIdx.x;
    if (j < 128) row[j] = G[g * 128 + j];
    __syncthreads();
    float acc = b[j];
    for (int k = 0; k < 128; ++k) acc += row[k] * W[j * 128 + k];
    G2[g * 256 + j] = elu_f(acc);
}

__global__ __launch_bounds__(64) void fc2_logsoftmax_kernel(
    const float* __restrict__ G2, const float* __restrict__ W,
    const float* __restrict__ b, float* __restrict__ out) {
    __shared__ float row[256];
    __shared__ float logits[10];
    __shared__ float red[2];
    int g = blockIdx.x;
    int tid = threadIdx.x;
    for (int i = tid; i < 256; i += 64) row[i] = G2[g * 256 + i];
    __syncthreads();
    if (tid < 10) {
        float acc = b[tid];
        for (int k = 0; k < 256; ++k) acc += row[k] * W[tid * 256 + k];
        logits[tid] = acc;
    }
    __syncthreads();
    if (tid == 0) {
        float m = -1e30f;
        for (int a = 0; a < 10; ++a) m = fmaxf(m, logits[a]);
        float s = 0.f;
        for (int a = 0; a < 10; ++a) s += expf(logits[a] - m);
        red[0] = m;
        red[1] = logf(s);
    }
    __syncthreads();
    if (tid < 10) out[g * 10 + tid] = logits[tid] - red[0] - red[1];
}

// ---------------------------------------------------------------------------

template <int C>
static void run_conv(unsigned short* Ahi, unsigned short* Alo,
                     unsigned short* Bhi, unsigned short* Blo,
                     unsigned short* Shi,
                     float* Wc, unsigned short* BsHi, unsigned short* BsLo,
                     const float* W, const float* wih, const float* whh,
                     const float* bih, const float* bhh,
                     const int* rowstart, const int* csr_src,
                     int N, int E, hipStream_t stream) {
    wc_kernel<C><<<(4 * C * 3 * C + 255) / 256, 256, 0, stream>>>(W, wih, Wc);
    swizzle_b2_kernel<C><<<(4 * 6 * C * C + 255) / 256, 256, 0, stream>>>(Wc, whh, BsHi, BsLo);
    constexpr int GPB = 2048 / C;  // gather dst-groups per block (C/8 lanes)
    int gblocks = (N + GPB - 1) / GPB;
    unsigned short *inHi = Ahi, *inLo = Alo, *outHi = Bhi, *outLo = Blo;
    for (int it = 0; it < 4; ++it) {
        gather_kernel<C><<<gblocks, 256, 0, stream>>>(
            inHi, rowstart, csr_src, Shi, N);
        const unsigned short* bs_h = BsHi + (size_t)it * 6 * C * C;
        const unsigned short* bs_l = BsLo + (size_t)it * 6 * C * C;
        if constexpr (C == 32) {
            int nb = (N + 63) / 64;
            gru32_kernel<<<nb, 256, 0, stream>>>(
                inHi, inLo, outHi, outLo, Shi, bs_h, bs_l, bih, bhh, N);
        } else {
            int nb = (N + 31) / 32;
            gru_mfma_kernel<C, 2><<<nb, 128, 0, stream>>>(
                inHi, inLo, outHi, outLo, Shi, bs_h, bs_l, bih, bhh, N);
        }
        unsigned short* tp;
        tp = inHi; inHi = outHi; outHi = tp;
        tp = inLo; inLo = outLo; outLo = tp;
    }
    // 4 iterations (even) -> final state back in (Ahi, Alo)
}

extern "C" void kernel_launch(void* const* d_in, const int* in_sizes, int n_in,
                              void* d_out, int out_size, void* d_ws, size_t ws_size,
                              hipStream_t stream) {
    const float* x = (const float*)d_in[0];
    const int* ei = (const int*)d_in[1];
    const int* batch = (const int*)d_in[2];
    const float* fc1W = (const float*)d_in[3];
    const float* fc1b = (const float*)d_in[4];
    const float* fc2W = (const float*)d_in[5];
    const float* fc2b = (const float*)d_in[6];
    const float* c1W = (const float*)d_in[7];
    const float* c1wih = (const float*)d_in[8];
    const float* c1whh = (const float*)d_in[9];
    const float* c1bih = (const float*)d_in[10];
    const float* c1bhh = (const float*)d_in[11];
    const float* c2W = (const float*)d_in[12];
    const float* c2wih = (const float*)d_in[13];
    const float* c2whh = (const float*)d_in[14];
    const float* c2bih = (const float*)d_in[15];
    const float* c2bhh = (const float*)d_in[16];
    const float* c3W = (const float*)d_in[17];
    const float* c3wih = (const float*)d_in[18];
    const float* c3whh = (const float*)d_in[19];
    const float* c3bih = (const float*)d_in[20];
    const float* c3bhh = (const float*)d_in[21];
    const float* bn1g = (const float*)d_in[22];
    const float* bn1b = (const float*)d_in[23];
    const float* bn1m = (const float*)d_in[24];
    const float* bn1v = (const float*)d_in[25];
    const float* bn2g = (const float*)d_in[26];
    const float* bn2b = (const float*)d_in[27];
    const float* bn2m = (const float*)d_in[28];
    const float* bn2v = (const float*)d_in[29];

    int N = in_sizes[0] / 32;
    int E = in_sizes[1] / 2;

    const size_t NB = (size_t)N * 128;  // shorts per plane
    unsigned short* PAhi = (unsigned short*)d_ws;  // state pair A
    unsigned short* PAlo = PAhi + NB;
    unsigned short* PBhi = PAlo + NB;              // state pair B (ping-pong)
    unsigned short* PBlo = PBhi + NB;
    unsigned short* Shi = PBlo + NB;               // gathered-S (hi-only)
    unsigned short* Slo = Shi + NB;                // (unused; kept for layout)
    unsigned short* BsHi = Slo + NB;               // 4 layers x 6*C*C <= 393216
    unsigned short* BsLo = BsHi + 393216;
    float* Wc = (float*)(BsLo + 393216);           // 4*C*3C <= 196608 floats
    float* G = Wc + 196608;
    float* G2 = G + 32768;
    int* deg = (int*)(G2 + 65536);
    int* scanout = deg + N;
    int* rowstart = scanout + N;
    int* writeptr = rowstart + N + 1;
    int* blockSums = writeptr + N;
    int* csr_src = blockSums + 64;

    // ---- build CSR by dst (once; reused by all 12 propagation steps) ----
    hipMemsetAsync(deg, 0, (size_t)N * sizeof(int), stream);
    int eblocks = (E + 255) / 256;
    hist_kernel<<<eblocks, 256, 0, stream>>>(ei, deg, E);
    int nscan = (N + 1023) / 1024;
    scan1_kernel<<<nscan, 256, 0, stream>>>(deg, scanout, blockSums, N);
    scan2_kernel<<<1, 64, 0, stream>>>(blockSums, nscan);
    scan3_kernel<<<(N + 255) / 256, 256, 0, stream>>>(scanout, blockSums, rowstart, writeptr, N, E);
    fill_kernel<<<eblocks, 256, 0, stream>>>(ei, writeptr, csr_src, E);

    // x -> pair A hi/lo ([N,32])
    init_x_kernel<<<(N * 32 + 255) / 256, 256, 0, stream>>>(x, PAhi, PAlo, N * 32);

    // conv1 (C=32): state PA, ping-pong with PB
    run_conv<32>(PAhi, PAlo, PBhi, PBlo, Shi, Wc, BsHi, BsLo,
                 c1W, c1wih, c1whh, c1bih, c1bhh, rowstart, csr_src, N, E, stream);
    elu_bn_pad_kernel<32, 64><<<(int)(((long)N * 64 + 255) / 256), 256, 0, stream>>>(
        PAhi, PAlo, PBhi, PBlo, bn1g, bn1b, bn1m, bn1v, N);

    // conv2 (C=64): state PB, ping-pong with PA
    run_conv<64>(PBhi, PBlo, PAhi, PAlo, Shi, Wc, BsHi, BsLo,
                 c2W, c2wih, c2whh, c2bih, c2bhh, rowstart, csr_src, N, E, stream);
    elu_bn_pad_kernel<64, 128><<<(int)(((long)N * 128 + 255) / 256), 256, 0, stream>>>(
        PBhi, PBlo, PAhi, PAlo, bn2g, bn2b, bn2m, bn2v, N);

    // conv3 (C=128): state PA, ping-pong with PB
    run_conv<128>(PAhi, PAlo, PBhi, PBlo, Shi, Wc, BsHi, BsLo,
                  c3W, c3wih, c3whh, c3bih, c3bhh, rowstart, csr_src, N, E, stream);

    // pool (reads pair A, stride 128)
    hipMemsetAsync(G, 0, 256 * 128 * sizeof(float), stream);
    pool_elu_kernel<<<(int)(((long)N * 128 + 255) / 256), 256, 0, stream>>>(
        PAhi, PAlo, batch, G, N);

    fc1_kernel<<<256, 256, 0, stream>>>(G, fc1W, fc1b, G2);
    fc2_logsoftmax_kernel<<<256, 64, 0, stream>>>(G2, fc2W, fc2b, (float*)d_out);
}

// Round 15
// 929.158 us; speedup vs baseline: 1.0496x; 1.0496x over previous
//
#include <hip/hip_runtime.h>
#include <math.h>

// ---------------------------------------------------------------------------
// GNN: 3x GatedGraphConv (C=32,64,128; 4 inner layers each) + BN + pool + MLP
// Round 15: REVERT to round-13 (best: 937 us). Round-14's 2-wave GRU blocks
// regressed (WRITE_SIZE 32->51 MB from fragmented write streams).
// Config: S hi-only bf16, H split hi/lo, hi-only gather reads, Wc fold,
// 4-wave/64-node GRU blocks, out-of-place ping-pong.
// ---------------------------------------------------------------------------

#define EPS_BN 1e-5f

typedef short short8 __attribute__((ext_vector_type(8)));
typedef unsigned short u16x8 __attribute__((ext_vector_type(8)));
typedef float f32x4 __attribute__((ext_vector_type(4)));

__device__ __forceinline__ float elu_f(float v) {
    return v > 0.f ? v : expm1f(v);
}
__device__ __forceinline__ float sigmoid_f(float v) {
    return 1.f / (1.f + __expf(-v));
}
__device__ __forceinline__ float tanh_f(float v) {
    float e = __expf(2.f * v);
    return 1.f - 2.f / (e + 1.f);
}
__device__ __forceinline__ unsigned short f2bf(float f) {
    unsigned u = __float_as_uint(f);
    unsigned r = (u + 0x7FFF + ((u >> 16) & 1)) >> 16;
    return (unsigned short)r;
}
__device__ __forceinline__ float bf2f(unsigned short b) {
    return __uint_as_float(((unsigned)b) << 16);
}
__device__ __forceinline__ void put_hl(unsigned short* __restrict__ hi,
                                       unsigned short* __restrict__ lo,
                                       size_t idx, float v) {
    unsigned short h = f2bf(v);
    hi[idx] = h;
    lo[idx] = f2bf(v - bf2f(h));
}

// ------------------------- CSR construction -------------------------------

__global__ __launch_bounds__(256) void hist_kernel(
    const int* __restrict__ ei, int* __restrict__ deg, int E) {
    int e = blockIdx.x * 256 + threadIdx.x;
    if (e < E) atomicAdd(&deg[ei[E + e]], 1);
}

__global__ __launch_bounds__(256) void scan1_kernel(
    const int* __restrict__ deg, int* __restrict__ out,
    int* __restrict__ blockSums, int N) {
    __shared__ int sdata[256];
    int b = blockIdx.x, t = threadIdx.x;
    int base = b * 1024 + t * 4;
    int v[4], s = 0;
#pragma unroll
    for (int i = 0; i < 4; ++i) {
        v[i] = (base + i < N) ? deg[base + i] : 0;
        s += v[i];
    }
    sdata[t] = s;
    __syncthreads();
    for (int off = 1; off < 256; off <<= 1) {
        int x = (t >= off) ? sdata[t - off] : 0;
        __syncthreads();
        sdata[t] += x;
        __syncthreads();
    }
    int run = sdata[t] - s;
#pragma unroll
    for (int i = 0; i < 4; ++i) {
        if (base + i < N) out[base + i] = run;
        run += v[i];
    }
    if (t == 255) blockSums[b] = sdata[255];
}

__global__ void scan2_kernel(int* blockSums, int nb) {
    if (threadIdx.x == 0 && blockIdx.x == 0) {
        int run = 0;
        for (int i = 0; i < nb; ++i) {
            int v = blockSums[i];
            blockSums[i] = run;
            run += v;
        }
    }
}

__global__ __launch_bounds__(256) void scan3_kernel(
    const int* __restrict__ out, const int* __restrict__ blockSums,
    int* __restrict__ rowstart, int* __restrict__ writeptr, int N, int E) {
    int i = blockIdx.x * 256 + threadIdx.x;
    if (i < N) {
        int v = out[i] + blockSums[i >> 10];
        rowstart[i] = v;
        writeptr[i] = v;
    }
    if (i == 0) rowstart[N] = E;
}

__global__ __launch_bounds__(256) void fill_kernel(
    const int* __restrict__ ei, int* __restrict__ writeptr,
    int* __restrict__ csr_src, int E) {
    int e = blockIdx.x * 256 + threadIdx.x;
    if (e < E) {
        int d = ei[E + e];
        int p = atomicAdd(&writeptr[d], 1);
        csr_src[p] = ei[e];
    }
}

// ------------------------- Wc = W[l] @ wih^T ------------------------------

template <int C>
__global__ __launch_bounds__(256) void wc_kernel(
    const float* __restrict__ W, const float* __restrict__ wih,
    float* __restrict__ Wc) {
    int idx = blockIdx.x * 256 + threadIdx.x;
    if (idx >= 4 * C * 3 * C) return;
    int l = idx / (C * 3 * C);
    int r = idx % (C * 3 * C);
    int k = r / (3 * C);
    int row = r % (3 * C);
    const float* wrow = W + ((size_t)l * C + k) * C;
    const float* irow = wih + (size_t)row * C;
    float acc = 0.f;
#pragma unroll 4
    for (int t = 0; t < C; ++t) acc += wrow[t] * irow[t];
    Wc[idx] = acc;
}

// ------------------------- B2 swizzle (hi/lo, all 4 layers) ---------------
// mfma_f32_16x16x32_bf16:
//   A[m][k]: m = lane&15, k = (lane>>4)*8 + j
//   B[k][n]: n = lane&15, k = (lane>>4)*8 + j
//   C/D:     col = lane&15, row = (lane>>4)*4 + reg
// GRU concat-B: K = 2C (k<C: Wc_l on S; k>=C: whh on H).
// tslot per ks: [0,CT): r ; [CT,2CT): z ; [2CT,3CT): k<C ? in : hn

template <int C>
__global__ __launch_bounds__(256) void swizzle_b2_kernel(
    const float* __restrict__ Wc, const float* __restrict__ whh,
    unsigned short* __restrict__ BsHi, unsigned short* __restrict__ BsLo) {
    constexpr int CT = C / 16;
    int idx = blockIdx.x * 256 + threadIdx.x;
    if (idx >= 4 * 6 * C * C) return;
    int l = idx / (6 * C * C);
    int r0 = idx % (6 * C * C);
    int j = r0 & 7;
    int lane = (r0 >> 3) & 63;
    int rest = r0 >> 9;
    int tslot = rest % (3 * CT);
    int ks = rest / (3 * CT);
    int k = ks * 32 + (lane >> 4) * 8 + j;
    int g = tslot / CT;
    int lt = tslot % CT;
    int c = lt * 16 + (lane & 15);
    int row = g * C + c;
    float v = (k < C) ? Wc[((size_t)l * C + k) * 3 * C + row]
                      : whh[(size_t)row * C + (k - C)];
    unsigned short h = f2bf(v);
    BsHi[idx] = h;
    BsLo[idx] = f2bf(v - bf2f(h));
}

// ------------------------- gather: S[d] = sum X[src] ----------------------
// LPG = C/8 lanes per dst, 16B loads, 4-edge unrolled pipeline.
// Reads only the HI plane of neighbors; sums fp32; writes S HI-ONLY.

template <int C>
__global__ __launch_bounds__(256) void gather_kernel(
    const unsigned short* __restrict__ Xhi,
    const int* __restrict__ rowstart, const int* __restrict__ csr_src,
    unsigned short* __restrict__ Shi, int N) {
    constexpr int LPG = C / 8;
    constexpr int GPB = 256 / LPG;
    int lane = threadIdx.x % LPG;
    int grp = threadIdx.x / LPG;
    int d = blockIdx.x * GPB + grp;
    if (d >= N) return;
    int p = rowstart[d];
    int p1 = rowstart[d + 1];
    float a[8];
#pragma unroll
    for (int j = 0; j < 8; ++j) a[j] = 0.f;
    int off = lane * 8;
    for (; p + 3 < p1; p += 4) {
        int s0 = csr_src[p];
        int s1 = csr_src[p + 1];
        int s2 = csr_src[p + 2];
        int s3 = csr_src[p + 3];
        u16x8 h0 = *(const u16x8*)(Xhi + (size_t)s0 * C + off);
        u16x8 h1 = *(const u16x8*)(Xhi + (size_t)s1 * C + off);
        u16x8 h2 = *(const u16x8*)(Xhi + (size_t)s2 * C + off);
        u16x8 h3 = *(const u16x8*)(Xhi + (size_t)s3 * C + off);
#pragma unroll
        for (int j = 0; j < 8; ++j) {
            a[j] += (bf2f(h0[j]) + bf2f(h1[j])) + (bf2f(h2[j]) + bf2f(h3[j]));
        }
    }
    for (; p < p1; ++p) {
        int s0 = csr_src[p];
        u16x8 h0 = *(const u16x8*)(Xhi + (size_t)s0 * C + off);
#pragma unroll
        for (int j = 0; j < 8; ++j) a[j] += bf2f(h0[j]);
    }
    size_t base = (size_t)d * C + off;
#pragma unroll
    for (int j = 0; j < 8; ++j) Shi[base + j] = f2bf(a[j]);
}

// ------------------------- GRU cell (C = 64 / 128) ------------------------
// Block = 4 waves = 64 nodes (4 A-tiles, shared through L1). Wave w owns
// column tiles [w*CTW,(w+1)*CTW) of every gate -> gate combine is
// wave-local. Out-of-place: reads Hin/S, writes Hout (no races).
// S-half: A hi-only (2 MFMA ops/acc). H-half: full split (3 ops/acc).
// NOTE: plain loads, compiler-scheduled — explicit prefetch regressed (r9);
// 2-wave blocks regressed (r14, fragmented writes).

template <int C, int MINW>
__global__ __launch_bounds__(256, MINW) void gru_mfma_kernel(
    const unsigned short* __restrict__ HinHi, const unsigned short* __restrict__ HinLo,
    unsigned short* __restrict__ HoutHi, unsigned short* __restrict__ HoutLo,
    const unsigned short* __restrict__ Shi,
    const unsigned short* __restrict__ BsHi, const unsigned short* __restrict__ BsLo,
    const float* __restrict__ biasI, const float* __restrict__ biasH, int N) {
    constexpr int CT = C / 16;
    constexpr int KS = C / 16;  // 2C/32 k-steps
    constexpr int CTW = CT / 4;
    int wave = threadIdx.x >> 6;
    int lane = threadIdx.x & 63;
    int quad = lane >> 4;
    int l16 = lane & 15;
    int node0 = blockIdx.x * 64;
    int arow[4];
#pragma unroll
    for (int t = 0; t < 4; ++t) {
        int r = node0 + t * 16 + l16;
        arow[t] = r < N ? r : N - 1;
    }
    f32x4 accR[CTW][4], accZ[CTW][4], accN[CTW][4], accH[CTW][4];
#pragma unroll
    for (int ct = 0; ct < CTW; ++ct)
#pragma unroll
        for (int t = 0; t < 4; ++t) {
            accR[ct][t] = (f32x4){0.f, 0.f, 0.f, 0.f};
            accZ[ct][t] = (f32x4){0.f, 0.f, 0.f, 0.f};
            accN[ct][t] = (f32x4){0.f, 0.f, 0.f, 0.f};
            accH[ct][t] = (f32x4){0.f, 0.f, 0.f, 0.f};
        }
    const short8* bhi = (const short8*)BsHi;
    const short8* blo = (const short8*)BsLo;

    // ---- S half (k < C): A = Shi only (2 MFMA ops per acc) ----
    for (int ks = 0; ks < KS / 2; ++ks) {
        int k0 = ks * 32 + quad * 8;
        short8 ahi[4];
#pragma unroll
        for (int t = 0; t < 4; ++t)
            ahi[t] = *(const short8*)(Shi + (size_t)arow[t] * C + k0);
#pragma unroll
        for (int ct = 0; ct < CTW; ++ct) {
            int ts = ks * 3 * CT + wave * CTW + ct;
            short8 bhf = bhi[(size_t)ts * 64 + lane];
            short8 blf = blo[(size_t)ts * 64 + lane];
#pragma unroll
            for (int t = 0; t < 4; ++t) {
                accR[ct][t] = __builtin_amdgcn_mfma_f32_16x16x32_bf16(ahi[t], bhf, accR[ct][t], 0, 0, 0);
                accR[ct][t] = __builtin_amdgcn_mfma_f32_16x16x32_bf16(ahi[t], blf, accR[ct][t], 0, 0, 0);
            }
            bhf = bhi[(size_t)(ts + CT) * 64 + lane];
            blf = blo[(size_t)(ts + CT) * 64 + lane];
#pragma unroll
            for (int t = 0; t < 4; ++t) {
                accZ[ct][t] = __builtin_amdgcn_mfma_f32_16x16x32_bf16(ahi[t], bhf, accZ[ct][t], 0, 0, 0);
                accZ[ct][t] = __builtin_amdgcn_mfma_f32_16x16x32_bf16(ahi[t], blf, accZ[ct][t], 0, 0, 0);
            }
            bhf = bhi[(size_t)(ts + 2 * CT) * 64 + lane];
            blf = blo[(size_t)(ts + 2 * CT) * 64 + lane];
#pragma unroll
            for (int t = 0; t < 4; ++t) {
                accN[ct][t] = __builtin_amdgcn_mfma_f32_16x16x32_bf16(ahi[t], bhf, accN[ct][t], 0, 0, 0);
                accN[ct][t] = __builtin_amdgcn_mfma_f32_16x16x32_bf16(ahi[t], blf, accN[ct][t], 0, 0, 0);
            }
        }
    }
    // ---- H half (k >= C): A = Hin hi/lo (3 MFMA ops per acc) ----
    for (int ks = KS / 2; ks < KS; ++ks) {
        int k0 = ks * 32 + quad * 8 - C;
        short8 ahi[4], alo[4];
#pragma unroll
        for (int t = 0; t < 4; ++t) {
            ahi[t] = *(const short8*)(HinHi + (size_t)arow[t] * C + k0);
            alo[t] = *(const short8*)(HinLo + (size_t)arow[t] * C + k0);
        }
#pragma unroll
        for (int ct = 0; ct < CTW; ++ct) {
            int ts = ks * 3 * CT + wave * CTW + ct;
            short8 bhf = bhi[(size_t)ts * 64 + lane];
            short8 blf = blo[(size_t)ts * 64 + lane];
#pragma unroll
            for (int t = 0; t < 4; ++t) {
                accR[ct][t] = __builtin_amdgcn_mfma_f32_16x16x32_bf16(ahi[t], bhf, accR[ct][t], 0, 0, 0);
                accR[ct][t] = __builtin_amdgcn_mfma_f32_16x16x32_bf16(alo[t], bhf, accR[ct][t], 0, 0, 0);
                accR[ct][t] = __builtin_amdgcn_mfma_f32_16x16x32_bf16(ahi[t], blf, accR[ct][t], 0, 0, 0);
            }
            bhf = bhi[(size_t)(ts + CT) * 64 + lane];
            blf = blo[(size_t)(ts + CT) * 64 + lane];
#pragma unroll
            for (int t = 0; t < 4; ++t) {
                accZ[ct][t] = __builtin_amdgcn_mfma_f32_16x16x32_bf16(ahi[t], bhf, accZ[ct][t], 0, 0, 0);
                accZ[ct][t] = __builtin_amdgcn_mfma_f32_16x16x32_bf16(alo[t], bhf, accZ[ct][t], 0, 0, 0);
                accZ[ct][t] = __builtin_amdgcn_mfma_f32_16x16x32_bf16(ahi[t], blf, accZ[ct][t], 0, 0, 0);
            }
            bhf = bhi[(size_t)(ts + 2 * CT) * 64 + lane];
            blf = blo[(size_t)(ts + 2 * CT) * 64 + lane];
#pragma unroll
            for (int t = 0; t < 4; ++t) {
                accH[ct][t] = __builtin_amdgcn_mfma_f32_16x16x32_bf16(ahi[t], bhf, accH[ct][t], 0, 0, 0);
                accH[ct][t] = __builtin_amdgcn_mfma_f32_16x16x32_bf16(alo[t], bhf, accH[ct][t], 0, 0, 0);
                accH[ct][t] = __builtin_amdgcn_mfma_f32_16x16x32_bf16(ahi[t], blf, accH[ct][t], 0, 0, 0);
            }
        }
    }

#pragma unroll
    for (int ct = 0; ct < CTW; ++ct) {
        int c = (wave * CTW + ct) * 16 + l16;
        float bir = biasI[c], biz = biasI[C + c], bin = biasI[2 * C + c];
        float bhr = biasH[c], bhz = biasH[C + c], bhn = biasH[2 * C + c];
#pragma unroll
        for (int t = 0; t < 4; ++t) {
#pragma unroll
            for (int r = 0; r < 4; ++r) {
                int node = node0 + t * 16 + quad * 4 + r;
                if (node < N) {
                    size_t gi = (size_t)node * C + c;
                    float xo = bf2f(HinHi[gi]) + bf2f(HinLo[gi]);
                    float rv = sigmoid_f(accR[ct][t][r] + bir + bhr);
                    float zv = sigmoid_f(accZ[ct][t][r] + biz + bhz);
                    float nv = tanh_f(accN[ct][t][r] + bin + rv * (accH[ct][t][r] + bhn));
                    put_hl(HoutHi, HoutLo, gi, (1.f - zv) * nv + zv * xo);
                }
            }
        }
    }
}

// C=32 GRU: 1 A-tile per wave, out-of-place; S hi-only
__global__ __launch_bounds__(256, 4) void gru32_kernel(
    const unsigned short* __restrict__ HinHi, const unsigned short* __restrict__ HinLo,
    unsigned short* __restrict__ HoutHi, unsigned short* __restrict__ HoutLo,
    const unsigned short* __restrict__ Shi,
    const unsigned short* __restrict__ BsHi, const unsigned short* __restrict__ BsLo,
    const float* __restrict__ biasI, const float* __restrict__ biasH, int N) {
    constexpr int C = 32;
    constexpr int CT = 2;
    int wave = threadIdx.x >> 6;
    int lane = threadIdx.x & 63;
    int quad = lane >> 4;
    int l16 = lane & 15;
    int node0 = blockIdx.x * 64 + wave * 16;
    int ar = node0 + l16;
    if (ar >= N) ar = N - 1;
    f32x4 accR[CT], accZ[CT], accN[CT], accH[CT];
#pragma unroll
    for (int t = 0; t < CT; ++t) {
        accR[t] = (f32x4){0.f, 0.f, 0.f, 0.f};
        accZ[t] = (f32x4){0.f, 0.f, 0.f, 0.f};
        accN[t] = (f32x4){0.f, 0.f, 0.f, 0.f};
        accH[t] = (f32x4){0.f, 0.f, 0.f, 0.f};
    }
    const short8* bhi = (const short8*)BsHi;
    const short8* blo = (const short8*)BsLo;
    int k0 = quad * 8;
    {  // ks = 0: S half (hi-only, 2 ops)
        short8 ahi = *(const short8*)(Shi + (size_t)ar * C + k0);
#pragma unroll
        for (int g = 0; g < 3; ++g) {
            f32x4* acc = g == 0 ? accR : (g == 1 ? accZ : accN);
#pragma unroll
            for (int t = 0; t < CT; ++t) {
                int ts = g * CT + t;
                short8 bhf = bhi[(size_t)ts * 64 + lane];
                short8 blf = blo[(size_t)ts * 64 + lane];
                acc[t] = __builtin_amdgcn_mfma_f32_16x16x32_bf16(ahi, bhf, acc[t], 0, 0, 0);
                acc[t] = __builtin_amdgcn_mfma_f32_16x16x32_bf16(ahi, blf, acc[t], 0, 0, 0);
            }
        }
    }
    {  // ks = 1: H half (full split, 3 ops)
        short8 ahi = *(const short8*)(HinHi + (size_t)ar * C + k0);
        short8 alo = *(const short8*)(HinLo + (size_t)ar * C + k0);
#pragma unroll
        for (int g = 0; g < 3; ++g) {
            f32x4* acc = g == 0 ? accR : (g == 1 ? accZ : accH);
#pragma unroll
            for (int t = 0; t < CT; ++t) {
                int ts = 3 * CT + g * CT + t;
                short8 bhf = bhi[(size_t)ts * 64 + lane];
                short8 blf = blo[(size_t)ts * 64 + lane];
                acc[t] = __builtin_amdgcn_mfma_f32_16x16x32_bf16(ahi, bhf, acc[t], 0, 0, 0);
                acc[t] = __builtin_amdgcn_mfma_f32_16x16x32_bf16(alo, bhf, acc[t], 0, 0, 0);
                acc[t] = __builtin_amdgcn_mfma_f32_16x16x32_bf16(ahi, blf, acc[t], 0, 0, 0);
            }
        }
    }
#pragma unroll
    for (int t = 0; t < CT; ++t) {
        int c = t * 16 + l16;
        float bir = biasI[c], biz = biasI[C + c], bin = biasI[2 * C + c];
        float bhr = biasH[c], bhz = biasH[C + c], bhn = biasH[2 * C + c];
#pragma unroll
        for (int r = 0; r < 4; ++r) {
            int node = node0 + quad * 4 + r;
            if (node < N) {
                size_t gi = (size_t)node * C + c;
                float xo = bf2f(HinHi[gi]) + bf2f(HinLo[gi]);
                float rv = sigmoid_f(accR[t][r] + bir + bhr);
                float zv = sigmoid_f(accZ[t][r] + biz + bhz);
                float nv = tanh_f(accN[t][r] + bin + rv * (accH[t][r] + bhn));
                put_hl(HoutHi, HoutLo, gi, (1.f - zv) * nv + zv * xo);
            }
        }
    }
}

// ------------------------- epilogues --------------------------------------

__global__ __launch_bounds__(256) void init_x_kernel(
    const float* __restrict__ x, unsigned short* __restrict__ Hhi,
    unsigned short* __restrict__ Hlo, int total) {
    int t = blockIdx.x * 256 + threadIdx.x;
    if (t < total) put_hl(Hhi, Hlo, t, x[t]);
}

template <int Cin, int Cout>
__global__ __launch_bounds__(256) void elu_bn_pad_kernel(
    const unsigned short* __restrict__ Shi, const unsigned short* __restrict__ Slo,
    unsigned short* __restrict__ Dhi, unsigned short* __restrict__ Dlo,
    const float* __restrict__ gamma, const float* __restrict__ beta,
    const float* __restrict__ mean, const float* __restrict__ var, int N) {
    long t = (long)blockIdx.x * 256 + threadIdx.x;
    long total = (long)N * Cout;
    if (t >= total) return;
    int n = (int)(t / Cout);
    int c = (int)(t & (Cout - 1));
    float v = 0.f;
    if (c < Cin) {
        size_t si = (size_t)n * Cin + c;
        float x = bf2f(Shi[si]) + bf2f(Slo[si]);
        x = elu_f(x);
        v = (x - mean[c]) * rsqrtf(var[c] + EPS_BN) * gamma[c] + beta[c];
    }
    put_hl(Dhi, Dlo, t, v);
}

__global__ __launch_bounds__(256) void pool_elu_kernel(
    const unsigned short* __restrict__ Hhi, const unsigned short* __restrict__ Hlo,
    const int* __restrict__ batch, float* __restrict__ G, int N) {
    long t = (long)blockIdx.x * 256 + threadIdx.x;
    if (t >= (long)N * 128) return;
    int n = (int)(t >> 7);
    int c = (int)(t & 127);
    float v = elu_f(bf2f(Hhi[t]) + bf2f(Hlo[t]));
    atomicAdd(&G[batch[n] * 128 + c], v);
}

__global__ __launch_bounds__(256) void fc1_kernel(
    const float* __restrict__ G, const float* __restrict__ W,
    const float* __restrict__ b, float* __restrict__ G2) {
    __shared__ float row[128];
    int g = blockIdx.x;
    int j = threadIdx.x;
    if (j < 128) row[j] = G[g * 128 + j];
    __syncthreads();
    float acc = b[j];
    for (int k = 0; k < 128; ++k) acc += row[k] * W[j * 128 + k];
    G2[g * 256 + j] = elu_f(acc);
}

__global__ __launch_bounds__(64) void fc2_logsoftmax_kernel(
    const float* __restrict__ G2, const float* __restrict__ W,
    const float* __restrict__ b, float* __restrict__ out) {
    __shared__ float row[256];
    __shared__ float logits[10];
    __shared__ float red[2];
    int g = blockIdx.x;
    int tid = threadIdx.x;
    for (int i = tid; i < 256; i += 64) row[i] = G2[g * 256 + i];
    __syncthreads();
    if (tid < 10) {
        float acc = b[tid];
        for (int k = 0; k < 256; ++k) acc += row[k] * W[tid * 256 + k];
        logits[tid] = acc;
    }
    __syncthreads();
    if (tid == 0) {
        float m = -1e30f;
        for (int a = 0; a < 10; ++a) m = fmaxf(m, logits[a]);
        float s = 0.f;
        for (int a = 0; a < 10; ++a) s += expf(logits[a] - m);
        red[0] = m;
        red[1] = logf(s);
    }
    __syncthreads();
    if (tid < 10) out[g * 10 + tid] = logits[tid] - red[0] - red[1];
}

// ---------------------------------------------------------------------------

template <int C>
static void run_conv(unsigned short* Ahi, unsigned short* Alo,
                     unsigned short* Bhi, unsigned short* Blo,
                     unsigned short* Shi,
                     float* Wc, unsigned short* BsHi, unsigned short* BsLo,
                     const float* W, const float* wih, const float* whh,
                     const float* bih, const float* bhh,
                     const int* rowstart, const int* csr_src,
                     int N, int E, hipStream_t stream) {
    wc_kernel<C><<<(4 * C * 3 * C + 255) / 256, 256, 0, stream>>>(W, wih, Wc);
    swizzle_b2_kernel<C><<<(4 * 6 * C * C + 255) / 256, 256, 0, stream>>>(Wc, whh, BsHi, BsLo);
    int nb = (N + 63) / 64;
    constexpr int GPB = 2048 / C;  // gather dst-groups per block (C/8 lanes)
    int gblocks = (N + GPB - 1) / GPB;
    unsigned short *inHi = Ahi, *inLo = Alo, *outHi = Bhi, *outLo = Blo;
    for (int it = 0; it < 4; ++it) {
        gather_kernel<C><<<gblocks, 256, 0, stream>>>(
            inHi, rowstart, csr_src, Shi, N);
        const unsigned short* bs_h = BsHi + (size_t)it * 6 * C * C;
        const unsigned short* bs_l = BsLo + (size_t)it * 6 * C * C;
        if constexpr (C == 32)
            gru32_kernel<<<nb, 256, 0, stream>>>(
                inHi, inLo, outHi, outLo, Shi, bs_h, bs_l, bih, bhh, N);
        else
            gru_mfma_kernel<C, (C == 128 ? 2 : 3)><<<nb, 256, 0, stream>>>(
                inHi, inLo, outHi, outLo, Shi, bs_h, bs_l, bih, bhh, N);
        unsigned short* tp;
        tp = inHi; inHi = outHi; outHi = tp;
        tp = inLo; inLo = outLo; outLo = tp;
    }
    // 4 iterations (even) -> final state back in (Ahi, Alo)
}

extern "C" void kernel_launch(void* const* d_in, const int* in_sizes, int n_in,
                              void* d_out, int out_size, void* d_ws, size_t ws_size,
                              hipStream_t stream) {
    const float* x = (const float*)d_in[0];
    const int* ei = (const int*)d_in[1];
    const int* batch = (const int*)d_in[2];
    const float* fc1W = (const float*)d_in[3];
    const float* fc1b = (const float*)d_in[4];
    const float* fc2W = (const float*)d_in[5];
    const float* fc2b = (const float*)d_in[6];
    const float* c1W = (const float*)d_in[7];
    const float* c1wih = (const float*)d_in[8];
    const float* c1whh = (const float*)d_in[9];
    const float* c1bih = (const float*)d_in[10];
    const float* c1bhh = (const float*)d_in[11];
    const float* c2W = (const float*)d_in[12];
    const float* c2wih = (const float*)d_in[13];
    const float* c2whh = (const float*)d_in[14];
    const float* c2bih = (const float*)d_in[15];
    const float* c2bhh = (const float*)d_in[16];
    const float* c3W = (const float*)d_in[17];
    const float* c3wih = (const float*)d_in[18];
    const float* c3whh = (const float*)d_in[19];
    const float* c3bih = (const float*)d_in[20];
    const float* c3bhh = (const float*)d_in[21];
    const float* bn1g = (const float*)d_in[22];
    const float* bn1b = (const float*)d_in[23];
    const float* bn1m = (const float*)d_in[24];
    const float* bn1v = (const float*)d_in[25];
    const float* bn2g = (const float*)d_in[26];
    const float* bn2b = (const float*)d_in[27];
    const float* bn2m = (const float*)d_in[28];
    const float* bn2v = (const float*)d_in[29];

    int N = in_sizes[0] / 32;
    int E = in_sizes[1] / 2;

    const size_t NB = (size_t)N * 128;  // shorts per plane
    unsigned short* PAhi = (unsigned short*)d_ws;  // state pair A
    unsigned short* PAlo = PAhi + NB;
    unsigned short* PBhi = PAlo + NB;              // state pair B (ping-pong)
    unsigned short* PBlo = PBhi + NB;
    unsigned short* Shi = PBlo + NB;               // gathered-S (hi-only)
    unsigned short* Slo = Shi + NB;                // (unused; kept for layout)
    unsigned short* BsHi = Slo + NB;               // 4 layers x 6*C*C <= 393216
    unsigned short* BsLo = BsHi + 393216;
    float* Wc = (float*)(BsLo + 393216);           // 4*C*3C <= 196608 floats
    float* G = Wc + 196608;
    float* G2 = G + 32768;
    int* deg = (int*)(G2 + 65536);
    int* scanout = deg + N;
    int* rowstart = scanout + N;
    int* writeptr = rowstart + N + 1;
    int* blockSums = writeptr + N;
    int* csr_src = blockSums + 64;

    // ---- build CSR by dst (once; reused by all 12 propagation steps) ----
    hipMemsetAsync(deg, 0, (size_t)N * sizeof(int), stream);
    int eblocks = (E + 255) / 256;
    hist_kernel<<<eblocks, 256, 0, stream>>>(ei, deg, E);
    int nscan = (N + 1023) / 1024;
    scan1_kernel<<<nscan, 256, 0, stream>>>(deg, scanout, blockSums, N);
    scan2_kernel<<<1, 64, 0, stream>>>(blockSums, nscan);
    scan3_kernel<<<(N + 255) / 256, 256, 0, stream>>>(scanout, blockSums, rowstart, writeptr, N, E);
    fill_kernel<<<eblocks, 256, 0, stream>>>(ei, writeptr, csr_src, E);

    // x -> pair A hi/lo ([N,32])
    init_x_kernel<<<(N * 32 + 255) / 256, 256, 0, stream>>>(x, PAhi, PAlo, N * 32);

    // conv1 (C=32): state PA, ping-pong with PB
    run_conv<32>(PAhi, PAlo, PBhi, PBlo, Shi, Wc, BsHi, BsLo,
                 c1W, c1wih, c1whh, c1bih, c1bhh, rowstart, csr_src, N, E, stream);
    elu_bn_pad_kernel<32, 64><<<(int)(((long)N * 64 + 255) / 256), 256, 0, stream>>>(
        PAhi, PAlo, PBhi, PBlo, bn1g, bn1b, bn1m, bn1v, N);

    // conv2 (C=64): state PB, ping-pong with PA
    run_conv<64>(PBhi, PBlo, PAhi, PAlo, Shi, Wc, BsHi, BsLo,
                 c2W, c2wih, c2whh, c2bih, c2bhh, rowstart, csr_src, N, E, stream);
    elu_bn_pad_kernel<64, 128><<<(int)(((long)N * 128 + 255) / 256), 256, 0, stream>>>(
        PBhi, PBlo, PAhi, PAlo, bn2g, bn2b, bn2m, bn2v, N);

    // conv3 (C=128): state PA, ping-pong with PB
    run_conv<128>(PAhi, PAlo, PBhi, PBlo, Shi, Wc, BsHi, BsLo,
                  c3W, c3wih, c3whh, c3bih, c3bhh, rowstart, csr_src, N, E, stream);

    // pool (reads pair A, stride 128)
    hipMemsetAsync(G, 0, 256 * 128 * sizeof(float), stream);
    pool_elu_kernel<<<(int)(((long)N * 128 + 255) / 256), 256, 0, stream>>>(
        PAhi, PAlo, batch, G, N);

    fc1_kernel<<<256, 256, 0, stream>>>(G, fc1W, fc1b, G2);
    fc2_logsoftmax_kernel<<<256, 64, 0, stream>>>(G2, fc2W, fc2b, (float*)d_out);
}